// Round 2
// baseline (1106.055 us; speedup 1.0000x reference)
//
#include <hip/hip_runtime.h>

typedef _Float16 f16;
typedef _Float16 f16x8 __attribute__((ext_vector_type(8)));
typedef float f32x4 __attribute__((ext_vector_type(4)));

#define NB 8
#define NC 128          // cin = cout
#define HW 256
#define EPSV 1e-8f

// LDS pitches in BYTES. 72 B = 36 f16 per row (32 used + 4 pad).
// addr/4 = 18*row + 4*k8 -> 16 distinct even bank residues per 16-lane group.
// Verified round 1: SQ_LDS_BANK_CONFLICT = 0 with this pitch (vs 2.8e7 at 64 B).
#define APITCH 72
#define XPITCH 72

// ---------------------------------------------------------------------------
// Kernel 1: gamma = y @ gamma_w^T + gamma_b; w = conv_w*(gamma+1); demod;
// write f16 W in layout [b][tap(9)][chunk(4)][co(128)][ci_in(32)]
// ---------------------------------------------------------------------------
__global__ __launch_bounds__(256) void k_weights(
    const float* __restrict__ y, const float* __restrict__ conv_w,
    const float* __restrict__ gamma_w, const float* __restrict__ gamma_b,
    f16* __restrict__ W16)
{
    int b  = blockIdx.x >> 7;
    int co = blockIdx.x & 127;
    int t  = threadIdx.x;

    __shared__ float g1[128];
    __shared__ float part[256];
    __shared__ float red[256];

    // gamma: each of 256 threads sums half a row
    {
        int ci = t & 127, hf = t >> 7;
        const float* yb = y + b * 128 + hf * 64;
        const float* gw = gamma_w + (size_t)ci * 128 + hf * 64;
        float s = 0.f;
        #pragma unroll 8
        for (int j = 0; j < 64; ++j) s += yb[j] * gw[j];
        part[t] = s;
    }
    __syncthreads();
    if (t < 128) g1[t] = part[t] + part[t + 128] + gamma_b[t] + 1.0f;
    __syncthreads();

    const float* wrow = conv_w + (size_t)co * 1152;
    float ssq = 0.f;
    for (int i = t; i < 1152; i += 256) {
        int ci = i / 9;
        float wv = wrow[i] * g1[ci];
        ssq += wv * wv;
    }
    red[t] = ssq;
    __syncthreads();
    for (int s = 128; s > 0; s >>= 1) {
        if (t < s) red[t] += red[t + s];
        __syncthreads();
    }
    float d = rsqrtf(red[0] + EPSV);

    for (int i = t; i < 1152; i += 256) {
        int ci = i / 9, tap = i - ci * 9;
        float wv = wrow[i] * g1[ci] * d;
        int chunk = ci >> 5, ci_in = ci & 31;
        size_t wi = (((size_t)((b * 9 + tap) * 4 + chunk) * 128 + co) << 5) + ci_in;
        W16[wi] = (f16)wv;
    }
}

// ---------------------------------------------------------------------------
// Kernel 2: x NCHW fp32 -> f16 layout [b][chunk(4)][y][x][ci_in(32)]
// COALESCED-WRITE version: one thread owns one pixel and writes its full
// 64 B (32 ci) contiguously -> a wave stores 4 KB contiguous (no partial-line
// write amplification; old version wrote 16 B at 64 B stride = 4x waste).
// Reads: per channel instruction, 256 lanes load 4 B consecutive = 1 KB
// coalesced segments.
// ---------------------------------------------------------------------------
__global__ __launch_bounds__(256) void k_transpose(
    const float* __restrict__ x, f16* __restrict__ x16)
{
    int b = blockIdx.x >> 8;
    int y = blockIdx.x & 255;
    int l = threadIdx.x;

    const float* src = x + (((size_t)b * 128) << 16) + ((size_t)y << 8) + l;

    #pragma unroll
    for (int chunk = 0; chunk < 4; ++chunk) {
        float v[32];
        #pragma unroll
        for (int j = 0; j < 32; ++j)
            v[j] = src[(size_t)(chunk * 32 + j) << 16];
        uint u[16];
        #pragma unroll
        for (int j = 0; j < 16; ++j) {
            f16 h0 = (f16)v[2 * j], h1 = (f16)v[2 * j + 1];
            ushort u0 = *(const ushort*)&h0, u1 = *(const ushort*)&h1;
            u[j] = (uint)u0 | ((uint)u1 << 16);
        }
        f16* dst = x16 + ((((size_t)(b * 4 + chunk) << 16) + ((size_t)y << 8) + l) << 5);
        uint4* d4 = (uint4*)dst;
        d4[0] = *(const uint4*)&u[0];
        d4[1] = *(const uint4*)&u[4];
        d4[2] = *(const uint4*)&u[8];
        d4[3] = *(const uint4*)&u[12];
    }
}

// ---------------------------------------------------------------------------
// Kernel 3: implicit-GEMM grouped conv. Block: 128 cout x (8 rows x 16 cols).
// K-loop: chunk(4) x tap(9); mfma_f32_16x16x32_f16; 4 waves 2x2, 64x64/wave.
// LDS tiles use 72 B pitch (bank-conflict-free, verified round 1).
// ---------------------------------------------------------------------------
__device__ __forceinline__ uint4 load_xs_g(const f16* xc, int idx, int y0, int x0)
{
    int r = idx / 72;                 // 72 granules (16B) per halo row
    int rem = idx - r * 72;
    int yy = y0 + r - 1;
    int xx = x0 + (rem >> 2) - 1;
    if ((unsigned)yy < 256u && (unsigned)xx < 256u)
        return *(const uint4*)(xc + ((((size_t)yy << 8) + xx) << 5) + ((rem & 3) << 3));
    return make_uint4(0u, 0u, 0u, 0u);
}

__device__ __forceinline__ void xs_write(char* __restrict__ xd, int idx, uint4 v)
{
    *(uint4*)(xd + (idx >> 2) * XPITCH + (idx & 3) * 16) = v;
}

__global__ __launch_bounds__(256) void k_conv(
    const f16* __restrict__ x16, const f16* __restrict__ W16,
    float* __restrict__ out)
{
    int blk  = blockIdx.x;
    int tile = blk & 511;
    int b    = blk >> 9;
    int tc   = tile & 15, tr = tile >> 4;
    int y0   = tr * 8, x0 = tc * 16;

    __shared__ char As[2][128 * APITCH];   // A tile: 128 co x 32 ci (padded pitch)
    __shared__ char Xs[2][180 * XPITCH];   // 10x18 halo pixels x 32 ci (padded pitch)

    int t    = threadIdx.x;
    int w    = t >> 6, lane = t & 63;
    int wm   = (w >> 1) * 64;         // cout base for this wave
    int wn   = (w & 1) * 4;           // output-row base for this wave
    int l15  = lane & 15;
    int k8   = lane >> 4;

    const f16* Wb = W16 + (size_t)b * 147456;   // 9*4*128*32

    // prologue: stage xs chunk0 -> buf0, A (tap0,chunk0) -> buf0
    {
        const f16* xc = x16 + (size_t)(b * 4) * 2097152;
        for (int idx = t; idx < 720; idx += 256) {
            uint4 v = load_xs_g(xc, idx, y0, x0);
            xs_write(&Xs[0][0], idx, v);
        }
        const uint4* asrc = (const uint4*)Wb;
        uint4* adst = (uint4*)(&As[0][0] + (t >> 1) * APITCH + (t & 1) * 32);
        adst[0] = asrc[(t >> 1) * 4 + (t & 1) * 2];
        adst[1] = asrc[(t >> 1) * 4 + (t & 1) * 2 + 1];
    }
    __syncthreads();

    f32x4 acc[4][4];
    #pragma unroll
    for (int mi = 0; mi < 4; ++mi)
        #pragma unroll
        for (int nj = 0; nj < 4; ++nj)
            acc[mi][nj] = (f32x4){0.f, 0.f, 0.f, 0.f};

    int chunk = 0, tap = 0;
    for (int it = 0; it < 36; ++it) {
        bool preA = it < 35;
        bool preX = (tap == 0) && (chunk < 3);

        // issue prefetch global loads early
        uint4 a0 = {}, a1 = {};
        if (preA) {
            int tn = tap + 1, cn = chunk;
            if (tn == 9) { tn = 0; cn = chunk + 1; }
            const uint4* asrc = (const uint4*)(Wb + (size_t)(tn * 4 + cn) * 4096);
            a0 = asrc[(t >> 1) * 4 + (t & 1) * 2];
            a1 = asrc[(t >> 1) * 4 + (t & 1) * 2 + 1];
        }
        uint4 xv0 = {}, xv1 = {}, xv2 = {};
        if (preX) {
            const f16* xc = x16 + (size_t)(b * 4 + chunk + 1) * 2097152;
            xv0 = load_xs_g(xc, t, y0, x0);
            xv1 = load_xs_g(xc, t + 256, y0, x0);
            if (t < 208) xv2 = load_xs_g(xc, t + 512, y0, x0);
        }

        // fragments
        int dy = tap / 3, dx = tap - dy * 3;
        const char* Ab = &As[it & 1][0];
        const char* Xb = &Xs[chunk & 1][0];

        f16x8 af[4];
        #pragma unroll
        for (int mi = 0; mi < 4; ++mi)
            af[mi] = *(const f16x8*)(Ab + (wm + mi * 16 + l15) * APITCH + k8 * 16);

        f16x8 bf[4];
        #pragma unroll
        for (int nj = 0; nj < 4; ++nj) {
            int p = (wn + nj + dy) * 18 + dx + l15;
            bf[nj] = *(const f16x8*)(Xb + p * XPITCH + k8 * 16);
        }

        #pragma unroll
        for (int mi = 0; mi < 4; ++mi)
            #pragma unroll
            for (int nj = 0; nj < 4; ++nj)
                acc[mi][nj] = __builtin_amdgcn_mfma_f32_16x16x32_f16(
                    af[mi], bf[nj], acc[mi][nj], 0, 0, 0);

        // drain prefetches into the other buffers
        if (preA) {
            uint4* adst = (uint4*)(&As[(it + 1) & 1][0] + (t >> 1) * APITCH + (t & 1) * 32);
            adst[0] = a0; adst[1] = a1;
        }
        if (preX) {
            char* xd = &Xs[(chunk + 1) & 1][0];
            xs_write(xd, t, xv0);
            xs_write(xd, t + 256, xv1);
            if (t < 208) xs_write(xd, t + 512, xv2);
        }
        __syncthreads();

        if (++tap == 9) { tap = 0; ++chunk; }
    }

    // epilogue: C/D layout col = lane&15 (pixel col), row = (lane>>4)*4 + reg (cout)
    size_t obase = (size_t)b << 23;   // b*128*65536
    #pragma unroll
    for (int mi = 0; mi < 4; ++mi) {
        #pragma unroll
        for (int r = 0; r < 4; ++r) {
            int co = wm + mi * 16 + k8 * 4 + r;
            float* orow = out + obase + ((size_t)co << 16);
            #pragma unroll
            for (int nj = 0; nj < 4; ++nj) {
                int yy = y0 + wn + nj;
                orow[(size_t)yy * 256 + x0 + l15] = acc[mi][nj][r];
            }
        }
    }
}

// ---------------------------------------------------------------------------
extern "C" void kernel_launch(void* const* d_in, const int* in_sizes, int n_in,
                              void* d_out, int out_size, void* d_ws, size_t ws_size,
                              hipStream_t stream)
{
    const float* x       = (const float*)d_in[0];
    const float* y       = (const float*)d_in[1];
    const float* conv_w  = (const float*)d_in[2];
    const float* gamma_w = (const float*)d_in[3];
    const float* gamma_b = (const float*)d_in[4];
    float* out = (float*)d_out;

    f16* x16 = (f16*)d_ws;                                    // 134,217,728 B
    f16* W16 = (f16*)((char*)d_ws + 134217728ull);            // 2,359,296 B

    k_weights<<<dim3(1024), dim3(256), 0, stream>>>(y, conv_w, gamma_w, gamma_b, W16);
    k_transpose<<<dim3(2048), dim3(256), 0, stream>>>(x, x16);
    k_conv<<<dim3(4096), dim3(256), 0, stream>>>(x16, W16, out);
}

// Round 3
// 655.607 us; speedup vs baseline: 1.6871x; 1.6871x over previous
//
#include <hip/hip_runtime.h>

typedef _Float16 f16;
typedef _Float16 f16x8 __attribute__((ext_vector_type(8)));
typedef float f32x4 __attribute__((ext_vector_type(4)));

#define NB 8
#define NC 128          // cin = cout
#define HW 256
#define EPSV 1e-8f

// LDS pitches in BYTES. MUST be a multiple of 16 (else compiler can't prove
// 16B alignment and splits every b128 -> round-2's 3x regression).
// 80 B = 20 dwords: row-start bank = 20*row mod 32 = 4*(5*row mod 8); 5 odd
// -> 8 consecutive rows cover 8 distinct granule starts = all 32 banks once
// per 8-lane phase. Aligned AND conflict-free.
#define APITCH 80
#define XPITCH 80

// ---------------------------------------------------------------------------
// Kernel 1: gamma = y @ gamma_w^T + gamma_b; w = conv_w*(gamma+1); demod;
// write f16 W in layout [b][tap(9)][chunk(4)][co(128)][ci_in(32)]
// ---------------------------------------------------------------------------
__global__ __launch_bounds__(256) void k_weights(
    const float* __restrict__ y, const float* __restrict__ conv_w,
    const float* __restrict__ gamma_w, const float* __restrict__ gamma_b,
    f16* __restrict__ W16)
{
    int b  = blockIdx.x >> 7;
    int co = blockIdx.x & 127;
    int t  = threadIdx.x;

    __shared__ float g1[128];
    __shared__ float part[256];
    __shared__ float red[256];

    // gamma: each of 256 threads sums half a row
    {
        int ci = t & 127, hf = t >> 7;
        const float* yb = y + b * 128 + hf * 64;
        const float* gw = gamma_w + (size_t)ci * 128 + hf * 64;
        float s = 0.f;
        #pragma unroll 8
        for (int j = 0; j < 64; ++j) s += yb[j] * gw[j];
        part[t] = s;
    }
    __syncthreads();
    if (t < 128) g1[t] = part[t] + part[t + 128] + gamma_b[t] + 1.0f;
    __syncthreads();

    const float* wrow = conv_w + (size_t)co * 1152;
    float ssq = 0.f;
    for (int i = t; i < 1152; i += 256) {
        int ci = i / 9;
        float wv = wrow[i] * g1[ci];
        ssq += wv * wv;
    }
    red[t] = ssq;
    __syncthreads();
    for (int s = 128; s > 0; s >>= 1) {
        if (t < s) red[t] += red[t + s];
        __syncthreads();
    }
    float d = rsqrtf(red[0] + EPSV);

    for (int i = t; i < 1152; i += 256) {
        int ci = i / 9, tap = i - ci * 9;
        float wv = wrow[i] * g1[ci] * d;
        int chunk = ci >> 5, ci_in = ci & 31;
        size_t wi = (((size_t)((b * 9 + tap) * 4 + chunk) * 128 + co) << 5) + ci_in;
        W16[wi] = (f16)wv;
    }
}

// ---------------------------------------------------------------------------
// Kernel 2: x NCHW fp32 -> f16 layout [b][chunk(4)][y][x][ci_in(32)]
// LDS-transpose version. Block = (b, y, x-quarter); tile = 64 px x 32 ci.
//   read : float4 per lane (16B), 4 x 256B contiguous segments per wave
//   LDS  : 64 px x 20 u32 (pitch 80 B, 16B-aligned rows); granule XOR-swizzle
//          on (px>>3)&3 -> write = 2 lanes/bank (free), read <= 2-way
//   write: 16B per lane, CONTIGUOUS 1KB per wave (old versions wrote 16B at
//          64B stride -> the ~400us transpose tax)
// ---------------------------------------------------------------------------
__global__ __launch_bounds__(256) void k_transpose(
    const float* __restrict__ x, f16* __restrict__ x16)
{
    int bid = blockIdx.x;                 // b*1024 + y*4 + xq
    int xq  = bid & 3;
    int yy  = (bid >> 2) & 255;
    int b   = bid >> 10;
    int x0  = xq * 64;

    int l = threadIdx.x;
    int g = l >> 4;        // ci-pair group 0..15 -> ci = {2g, 2g+1}
    int q = l & 15;        // px-quad: px = x0 + 4q + j

    __shared__ __attribute__((aligned(16))) uint Ts[64 * 20];   // [px][20 u32]

    int px_l = l >> 2;     // read-phase pixel 0..63
    int part = l & 3;      // read-phase 16B granule (8 ci)

    for (int chunk = 0; chunk < 4; ++chunk) {
        const float* s0 = x + (((size_t)(b * 128 + chunk * 32 + 2 * g)) << 16)
                            + ((size_t)yy << 8) + x0 + 4 * q;
        float4 v0 = *(const float4*)s0;              // ci = 2g
        float4 v1 = *(const float4*)(s0 + 65536);    // ci = 2g+1

        uint u[4];
        {
            const float* a = (const float*)&v0;
            const float* c = (const float*)&v1;
            #pragma unroll
            for (int j = 0; j < 4; ++j) {
                f16 h0 = (f16)a[j], h1 = (f16)c[j];
                ushort u0 = *(const ushort*)&h0, u1 = *(const ushort*)&h1;
                u[j] = (uint)u0 | ((uint)u1 << 16);
            }
        }
        // physical granule = logical granule (g>>2) XOR ((px>>3)&3); px=4q+j
        // so (px>>3)&3 = (q>>1)&3.
        int pg = (((g >> 2) ^ (q >> 1)) & 3);
        #pragma unroll
        for (int j = 0; j < 4; ++j) {
            int px = 4 * q + j;
            Ts[px * 20 + pg * 4 + (g & 3)] = u[j];
        }
        __syncthreads();

        uint4 val = *(const uint4*)&Ts[px_l * 20 + ((part ^ ((px_l >> 3) & 3)) << 2)];
        f16* dst = x16 + ((((size_t)(b * 4 + chunk) << 16) + ((size_t)yy << 8)
                           + x0 + px_l) << 5) + part * 8;
        *(uint4*)dst = val;
        if (chunk < 3) __syncthreads();
    }
}

// ---------------------------------------------------------------------------
// Kernel 3: implicit-GEMM grouped conv. Block: 128 cout x (8 rows x 16 cols).
// K-loop: chunk(4) x tap(9); mfma_f32_16x16x32_f16; 4 waves 2x2, 64x64/wave.
// LDS tiles: 80 B pitch (16B-aligned AND bank-conflict-free; see top).
// ---------------------------------------------------------------------------
__device__ __forceinline__ uint4 load_xs_g(const f16* xc, int idx, int y0, int x0)
{
    int r = idx / 72;                 // 72 granules (16B) per halo row
    int rem = idx - r * 72;
    int yy = y0 + r - 1;
    int xx = x0 + (rem >> 2) - 1;
    if ((unsigned)yy < 256u && (unsigned)xx < 256u)
        return *(const uint4*)(xc + ((((size_t)yy << 8) + xx) << 5) + ((rem & 3) << 3));
    return make_uint4(0u, 0u, 0u, 0u);
}

__device__ __forceinline__ void xs_write(char* __restrict__ xd, int idx, uint4 v)
{
    *(uint4*)(xd + (idx >> 2) * XPITCH + (idx & 3) * 16) = v;
}

__global__ __launch_bounds__(256) void k_conv(
    const f16* __restrict__ x16, const f16* __restrict__ W16,
    float* __restrict__ out)
{
    int blk  = blockIdx.x;
    int tile = blk & 511;
    int b    = blk >> 9;
    int tc   = tile & 15, tr = tile >> 4;
    int y0   = tr * 8, x0 = tc * 16;

    __shared__ __attribute__((aligned(16))) char As[2][128 * APITCH];
    __shared__ __attribute__((aligned(16))) char Xs[2][180 * XPITCH];

    int t    = threadIdx.x;
    int w    = t >> 6, lane = t & 63;
    int wm   = (w >> 1) * 64;         // cout base for this wave
    int wn   = (w & 1) * 4;           // output-row base for this wave
    int l15  = lane & 15;
    int k8   = lane >> 4;

    const f16* Wb = W16 + (size_t)b * 147456;   // 9*4*128*32

    // prologue: stage xs chunk0 -> buf0, A (tap0,chunk0) -> buf0
    {
        const f16* xc = x16 + (size_t)(b * 4) * 2097152;
        for (int idx = t; idx < 720; idx += 256) {
            uint4 v = load_xs_g(xc, idx, y0, x0);
            xs_write(&Xs[0][0], idx, v);
        }
        const uint4* asrc = (const uint4*)Wb;
        uint4* adst = (uint4*)(&As[0][0] + (t >> 1) * APITCH + (t & 1) * 32);
        adst[0] = asrc[(t >> 1) * 4 + (t & 1) * 2];
        adst[1] = asrc[(t >> 1) * 4 + (t & 1) * 2 + 1];
    }
    __syncthreads();

    f32x4 acc[4][4];
    #pragma unroll
    for (int mi = 0; mi < 4; ++mi)
        #pragma unroll
        for (int nj = 0; nj < 4; ++nj)
            acc[mi][nj] = (f32x4){0.f, 0.f, 0.f, 0.f};

    int chunk = 0, tap = 0;
    for (int it = 0; it < 36; ++it) {
        bool preA = it < 35;
        bool preX = (tap == 0) && (chunk < 3);

        // issue prefetch global loads early
        uint4 a0 = {}, a1 = {};
        if (preA) {
            int tn = tap + 1, cn = chunk;
            if (tn == 9) { tn = 0; cn = chunk + 1; }
            const uint4* asrc = (const uint4*)(Wb + (size_t)(tn * 4 + cn) * 4096);
            a0 = asrc[(t >> 1) * 4 + (t & 1) * 2];
            a1 = asrc[(t >> 1) * 4 + (t & 1) * 2 + 1];
        }
        uint4 xv0 = {}, xv1 = {}, xv2 = {};
        if (preX) {
            const f16* xc = x16 + (size_t)(b * 4 + chunk + 1) * 2097152;
            xv0 = load_xs_g(xc, t, y0, x0);
            xv1 = load_xs_g(xc, t + 256, y0, x0);
            if (t < 208) xv2 = load_xs_g(xc, t + 512, y0, x0);
        }

        // fragments
        int dy = tap / 3, dx = tap - dy * 3;
        const char* Ab = &As[it & 1][0];
        const char* Xb = &Xs[chunk & 1][0];

        f16x8 af[4];
        #pragma unroll
        for (int mi = 0; mi < 4; ++mi)
            af[mi] = *(const f16x8*)(Ab + (wm + mi * 16 + l15) * APITCH + k8 * 16);

        f16x8 bf[4];
        #pragma unroll
        for (int nj = 0; nj < 4; ++nj) {
            int p = (wn + nj + dy) * 18 + dx + l15;
            bf[nj] = *(const f16x8*)(Xb + p * XPITCH + k8 * 16);
        }

        #pragma unroll
        for (int mi = 0; mi < 4; ++mi)
            #pragma unroll
            for (int nj = 0; nj < 4; ++nj)
                acc[mi][nj] = __builtin_amdgcn_mfma_f32_16x16x32_f16(
                    af[mi], bf[nj], acc[mi][nj], 0, 0, 0);

        // drain prefetches into the other buffers
        if (preA) {
            uint4* adst = (uint4*)(&As[(it + 1) & 1][0] + (t >> 1) * APITCH + (t & 1) * 32);
            adst[0] = a0; adst[1] = a1;
        }
        if (preX) {
            char* xd = &Xs[(chunk + 1) & 1][0];
            xs_write(xd, t, xv0);
            xs_write(xd, t + 256, xv1);
            if (t < 208) xs_write(xd, t + 512, xv2);
        }
        __syncthreads();

        if (++tap == 9) { tap = 0; ++chunk; }
    }

    // epilogue: C/D layout col = lane&15 (pixel col), row = (lane>>4)*4 + reg (cout)
    size_t obase = (size_t)b << 23;   // b*128*65536
    #pragma unroll
    for (int mi = 0; mi < 4; ++mi) {
        #pragma unroll
        for (int r = 0; r < 4; ++r) {
            int co = wm + mi * 16 + k8 * 4 + r;
            float* orow = out + obase + ((size_t)co << 16);
            #pragma unroll
            for (int nj = 0; nj < 4; ++nj) {
                int yy = y0 + wn + nj;
                orow[(size_t)yy * 256 + x0 + l15] = acc[mi][nj][r];
            }
        }
    }
}

// ---------------------------------------------------------------------------
extern "C" void kernel_launch(void* const* d_in, const int* in_sizes, int n_in,
                              void* d_out, int out_size, void* d_ws, size_t ws_size,
                              hipStream_t stream)
{
    const float* x       = (const float*)d_in[0];
    const float* y       = (const float*)d_in[1];
    const float* conv_w  = (const float*)d_in[2];
    const float* gamma_w = (const float*)d_in[3];
    const float* gamma_b = (const float*)d_in[4];
    float* out = (float*)d_out;

    f16* x16 = (f16*)d_ws;                                    // 134,217,728 B
    f16* W16 = (f16*)((char*)d_ws + 134217728ull);            // 2,359,296 B

    k_weights<<<dim3(1024), dim3(256), 0, stream>>>(y, conv_w, gamma_w, gamma_b, W16);
    k_transpose<<<dim3(8192), dim3(256), 0, stream>>>(x, x16);
    k_conv<<<dim3(4096), dim3(256), 0, stream>>>(x16, W16, out);
}